// Round 14
// baseline (460.646 us; speedup 1.0000x reference)
//
#include <hip/hip_runtime.h>
#include <math.h>

#define NEXP 32
#define NTOK 256
#define DIMD 768
#define DHID 2048
#define DBOT 256
#define DOUT 768
#define NSLOT 512

// ---------------- gate: logits -> top2 -> normalized weights ----------------
__global__ __launch_bounds__(64) void gate_kernel(
    const float* __restrict__ x, const float* __restrict__ gw,
    int* __restrict__ topk_idx, float* __restrict__ topk_w) {
  const int n = blockIdx.x;
  const int l = threadIdx.x;
  const float* xr = x + n * DIMD;
  float xs[12];
#pragma unroll
  for (int j = 0; j < 12; j++) xs[j] = xr[l + 64 * j];
  float logit[NEXP];
#pragma unroll
  for (int e = 0; e < NEXP; e++) {
    const float* g = gw + e * DIMD;
    float p = 0.f;
#pragma unroll
    for (int j = 0; j < 12; j++) p = fmaf(xs[j], g[l + 64 * j], p);
#pragma unroll
    for (int m = 1; m < 64; m <<= 1) p += __shfl_xor(p, m);
    logit[e] = p;
  }
  int i0 = 0; float m0 = logit[0];
#pragma unroll
  for (int e = 1; e < NEXP; e++) { if (logit[e] > m0) { m0 = logit[e]; i0 = e; } }
  int i1 = -1; float m1 = -3.4e38f;
#pragma unroll
  for (int e = 0; e < NEXP; e++) { if (e != i0 && logit[e] > m1) { m1 = logit[e]; i1 = e; } }
  const float e1 = expf(m1 - m0);
  const float w0 = 1.f / (1.f + e1);
  const float w1 = e1 * w0;
  if (l == 0) {
    topk_idx[2 * n] = i0; topk_idx[2 * n + 1] = i1;
    topk_w[2 * n] = w0;  topk_w[2 * n + 1] = w1;
  }
}

// ---------------- build per-expert token lists + maps ----------------
__global__ __launch_bounds__(256) void build_lists(
    const int* __restrict__ topk_idx,
    int* __restrict__ counts, int* __restrict__ offsets,
    int* __restrict__ tok_list, int* __restrict__ tok2slot) {
  __shared__ int cnt[NEXP], base[NEXP], fill[NEXP];
  const int t = threadIdx.x;
  if (t < NEXP) { cnt[t] = 0; fill[t] = 0; }
  __syncthreads();
  const int e0 = topk_idx[2 * t], e1 = topk_idx[2 * t + 1];
  atomicAdd(&cnt[e0], 1);
  atomicAdd(&cnt[e1], 1);
  __syncthreads();
  if (t == 0) { int s = 0; for (int i = 0; i < NEXP; i++) { base[i] = s; s += cnt[i]; } }
  __syncthreads();
  const int p0 = atomicAdd(&fill[e0], 1);
  tok_list[base[e0] + p0] = t; tok2slot[2 * t] = base[e0] + p0;
  const int p1 = atomicAdd(&fill[e1], 1);
  tok_list[base[e1] + p1] = t; tok2slot[2 * t + 1] = base[e1] + p1;
  if (t < NEXP) { counts[t] = cnt[t]; offsets[t] = base[t]; }
}

__device__ __forceinline__ float gelu_f(float v) {
  return 0.5f * v * (1.f + erff(v * 0.70710678118654752f));
}

#define FMA4(A, XS, WV) \
  A.x = fmaf(XS, WV.x, A.x); A.y = fmaf(XS, WV.y, A.y); \
  A.z = fmaf(XS, WV.z, A.z); A.w = fmaf(XS, WV.w, A.w)
#define ADD4(Q, P) Q.x += P.x; Q.y += P.y; Q.z += P.z; Q.w += P.w

// ---------------- expert FF layer: W streamed via global_load_lds, TPT=8 ----------------
// Block 256 thr = 4 waves; wave owns 8 tokens; lane owns 4 cols (256-col tile).
// Per row per wave: 1 distinct ds_read_b128 (W) + 2 broadcast b128 (act) + 32 FMA.
// LDS/section ~5.1K cy < HBM fair-share 6.4K cy (R13's TPT=4 layout was 8.2K: 8 waves
// redundantly re-reading identical W data -> LDS-bound). HBM is now the binding pipe.
// 64-row sections, double-buffered; act staged T14-style (issue early, ds_write late).
// Direct stores only (no atomics):
// MODE 0: B1 = gelu(x(gather) @ W1 + b1)            grid (8,32)  K=768
// MODE 1: B2 = gelu(B1 @ W2 + b2)                   grid (8,32)  K=2048
// MODE 2: zpart[kb] = B2 @ W3 K-slice               grid (8,32)  K=256/block
// MODE 3: OutS = (sum_k zpart[k] + b3) @ Wl         grid (3,32)  K=256 (zsum folded)
template <int MODE>
__global__ __launch_bounds__(256) void ff_kernel(
    const float* __restrict__ Ain, const float* __restrict__ W,
    const float* __restrict__ Bias, float* __restrict__ Out,
    const float* __restrict__ zpart,
    const int* __restrict__ offsets, const int* __restrict__ counts,
    const int* __restrict__ tok_list) {
  constexpr int NCT   = (MODE <= 1) ? 2048 : (MODE == 2) ? 256 : 768;
  constexpr int KFULL = (MODE == 0) ? 768 : (MODE == 3) ? 256 : 2048;
  constexpr int INS   = (MODE == 0) ? DIMD : DHID;
  constexpr int NSEC  = (MODE == 0) ? 12 : (MODE == 1) ? 32 : 4;
  __shared__ float Wlds[2 * 64 * 256];   // 128 KB dbuf weight tile
  __shared__ float act_t[2 * 64 * 32];   // 16 KB dbuf act (transposed [row][tok])
  const int tid  = threadIdx.x;
  const int lane = tid & 63;
  const int wave = tid >> 6;           // 0..3 = token group of 8
  const int e    = blockIdx.y;
  const int kb   = (MODE == 2) ? blockIdx.x : 0;
  const int ct   = (MODE == 2) ? 0 : blockIdx.x;
  const int kbase = kb * 256;
  const int cnt = counts[e];
  const int off = offsets[e];
  const int col = ct * 256 + lane * 4;
  const float* Wsrc = W + (size_t)e * KFULL * NCT + (size_t)ct * 256;
  const int tok  = tid & 31;
  const int kseg = tid >> 5;           // 0..7: stages act rows kseg*8..+7

  for (int tc0 = 0; tc0 < cnt; tc0 += 32) {
    const int tcn = min(32, cnt - tc0);
    const int slot = off + tc0 + tok;
    const float* Arow = nullptr;
    if (tok < tcn && MODE != 3) {
      const int row = (MODE == 0) ? tok_list[slot] : slot;
      Arow = Ain + (size_t)row * INS + kbase;
    }

    float4 acc[8];
#pragma unroll
    for (int t = 0; t < 8; t++) acc[t] = {0.f, 0.f, 0.f, 0.f};
    float4 av0 = {0.f, 0.f, 0.f, 0.f}, av1 = {0.f, 0.f, 0.f, 0.f};

    // ---- staging helpers ----
    auto a_issue = [&](int s) {          // load this thread's 8 act floats (early)
      const int base = s * 64 + kseg * 8;
      if (MODE == 3) {
        if (tok < tcn) {
          float4 q0 = *(const float4*)(Bias + (size_t)e * DBOT + base);
          float4 q1 = *(const float4*)(Bias + (size_t)e * DBOT + base + 4);
#pragma unroll
          for (int k = 0; k < 8; k++) {
            const float* zp = zpart + ((size_t)k * NSLOT + slot) * DBOT + base;
            const float4 p0 = *(const float4*)(zp);
            const float4 p1 = *(const float4*)(zp + 4);
            ADD4(q0, p0); ADD4(q1, p1);
          }
          av0 = q0; av1 = q1;
        } else {
          av0 = {0.f, 0.f, 0.f, 0.f}; av1 = {0.f, 0.f, 0.f, 0.f};
        }
      } else {
        if (Arow) {
          av0 = *(const float4*)(Arow + base);
          av1 = *(const float4*)(Arow + base + 4);
        } else {
          av0 = {0.f, 0.f, 0.f, 0.f}; av1 = {0.f, 0.f, 0.f, 0.f};
        }
      }
    };
    auto w_issue = [&](int b, int s) {   // 16 gload_lds calls: 64 rows x 1 KB
      float* wl = Wlds + b * 16384;
      const float* src = Wsrc + (size_t)(kbase + s * 64) * NCT;
#pragma unroll
      for (int c = 0; c < 16; c++) {
        const int r = c * 4 + wave;
        __builtin_amdgcn_global_load_lds(
            (const __attribute__((address_space(1))) void*)(src + (size_t)r * NCT + lane * 4),
            (__attribute__((address_space(3))) void*)(wl + r * 256),
            16, 0, 0);
      }
    };
    auto a_write = [&](int b) {          // transposed ds_writes (late); 2-way free
      float* at = act_t + b * 2048;
      at[(kseg * 8 + 0) * 32 + tok] = av0.x;
      at[(kseg * 8 + 1) * 32 + tok] = av0.y;
      at[(kseg * 8 + 2) * 32 + tok] = av0.z;
      at[(kseg * 8 + 3) * 32 + tok] = av0.w;
      at[(kseg * 8 + 4) * 32 + tok] = av1.x;
      at[(kseg * 8 + 5) * 32 + tok] = av1.y;
      at[(kseg * 8 + 6) * 32 + tok] = av1.z;
      at[(kseg * 8 + 7) * 32 + tok] = av1.w;
    };

    // ---- prologue ----
    a_issue(0);
    w_issue(0, 0);
    a_write(0);
    __syncthreads();

    // ---- section loop ----
    for (int s = 0; s < NSEC; s++) {
      const int b = s & 1;
      if (s + 1 < NSEC) {
        a_issue(s + 1);
        w_issue(b ^ 1, s + 1);   // fire-and-forget queue rides through compute
      }
      {  // ---- compute: 64 rows ----
        const float* wl = Wlds + b * 16384 + lane * 4;
        const float* at = act_t + b * 2048 + wave * 8;
#pragma unroll 8
        for (int r = 0; r < 64; r++) {
          const float4 wv = *(const float4*)(wl + r * 256);       // distinct 1 KB/wave
          const float4 x0 = *(const float4*)(at + r * 32);        // broadcast
          const float4 x1 = *(const float4*)(at + r * 32 + 4);    // broadcast
          FMA4(acc[0], x0.x, wv);
          FMA4(acc[1], x0.y, wv);
          FMA4(acc[2], x0.z, wv);
          FMA4(acc[3], x0.w, wv);
          FMA4(acc[4], x1.x, wv);
          FMA4(acc[5], x1.y, wv);
          FMA4(acc[6], x1.z, wv);
          FMA4(acc[7], x1.w, wv);
        }
      }
      if (s + 1 < NSEC) a_write(b ^ 1);
      __syncthreads();
    }

    // ---- epilogue: direct stores, static indexing ----
    float4 bv = {0.f, 0.f, 0.f, 0.f};
    if (MODE <= 1) bv = *(const float4*)(Bias + (size_t)e * NCT + col);
#pragma unroll
    for (int tt = 0; tt < 8; tt++) {
      if (wave * 8 + tt < tcn) {
        const int os = off + tc0 + wave * 8 + tt;
        float4 o = acc[tt];
        if (MODE <= 1) {
          o.x = gelu_f(o.x + bv.x); o.y = gelu_f(o.y + bv.y);
          o.z = gelu_f(o.z + bv.z); o.w = gelu_f(o.w + bv.w);
          *(float4*)(Out + (size_t)os * NCT + col) = o;
        } else if (MODE == 2) {
          *(float4*)(Out + ((size_t)kb * NSLOT + os) * DBOT + lane * 4) = o;
        } else {
          *(float4*)(Out + (size_t)os * DOUT + col) = o;
        }
      }
    }
    __syncthreads();   // buffers free before next chunk
  }
}

// ---------------- combine: y[n] = sum_k w_k * (OutS[slot_k] + bl[e_k]) ----------------
__global__ __launch_bounds__(192) void combine_kernel(
    const float* __restrict__ OutS, const float* __restrict__ bl,
    const int* __restrict__ topk_idx, const float* __restrict__ topk_w,
    const int* __restrict__ tok2slot, float* __restrict__ y) {
  const int n = blockIdx.x;
  const int c = threadIdx.x * 4;
  const int s0 = tok2slot[2 * n], s1 = tok2slot[2 * n + 1];
  const int e0 = topk_idx[2 * n], e1 = topk_idx[2 * n + 1];
  const float w0 = topk_w[2 * n], w1 = topk_w[2 * n + 1];
  const float4 a  = *(const float4*)(OutS + (size_t)s0 * DOUT + c);
  const float4 b  = *(const float4*)(OutS + (size_t)s1 * DOUT + c);
  const float4 ba = *(const float4*)(bl + (size_t)e0 * DOUT + c);
  const float4 bb = *(const float4*)(bl + (size_t)e1 * DOUT + c);
  float4 o;
  o.x = w0 * (a.x + ba.x) + w1 * (b.x + bb.x);
  o.y = w0 * (a.y + ba.y) + w1 * (b.y + bb.y);
  o.z = w0 * (a.z + ba.z) + w1 * (b.z + bb.z);
  o.w = w0 * (a.w + ba.w) + w1 * (b.w + bb.w);
  *(float4*)(y + (size_t)n * DOUT + c) = o;
}

extern "C" void kernel_launch(void* const* d_in, const int* in_sizes, int n_in,
                              void* d_out, int out_size, void* d_ws, size_t ws_size,
                              hipStream_t stream) {
  const float* x  = (const float*)d_in[0];
  const float* gw = (const float*)d_in[1];
  const float* W1 = (const float*)d_in[2];
  const float* b1 = (const float*)d_in[3];
  const float* W2 = (const float*)d_in[4];
  const float* b2 = (const float*)d_in[5];
  const float* W3 = (const float*)d_in[6];
  const float* b3 = (const float*)d_in[7];
  const float* Wl = (const float*)d_in[8];
  const float* bl = (const float*)d_in[9];
  float* y  = (float*)d_out;
  float* ws = (float*)d_ws;

  float* topk_w   = ws;                    // 512 f
  int*   topk_idx = (int*)(ws + 512);      // 512 i
  int*   counts   = (int*)(ws + 1024);     // 32 i
  int*   offsets  = (int*)(ws + 1056);     // 32 i
  int*   tok_list = (int*)(ws + 1088);     // 512 i
  int*   tok2slot = (int*)(ws + 1600);     // 512 i
  float* B1    = ws + 4096;                        // 512*2048
  float* B2    = B1 + (size_t)NSLOT * DHID;        // 512*2048
  float* zpart = B2 + (size_t)NSLOT * DHID;        // 8*512*256
  float* OutS  = zpart + (size_t)8 * NSLOT * DBOT; // 512*768

  gate_kernel<<<NTOK, 64, 0, stream>>>(x, gw, topk_idx, topk_w);
  build_lists<<<1, 256, 0, stream>>>(topk_idx, counts, offsets, tok_list, tok2slot);
  // L1: B1 = gelu(x @ W1 + b1)        (8 coltiles x 32 experts, K=768)
  ff_kernel<0><<<dim3(8, 32), 256, 0, stream>>>(x,  W1, b1, B1, nullptr,
                                                offsets, counts, tok_list);
  // L2: B2 = gelu(B1 @ W2 + b2)       (8 coltiles x 32 experts, K=2048)
  ff_kernel<1><<<dim3(8, 32), 256, 0, stream>>>(B1, W2, b2, B2, nullptr,
                                                offsets, counts, tok_list);
  // L3: zpart[kb] = B2 @ W3 slice     (8 K-slices x 32 experts)
  ff_kernel<2><<<dim3(8, 32), 256, 0, stream>>>(B2, W3, nullptr, zpart, nullptr,
                                                offsets, counts, tok_list);
  // L4: OutS = (sum zpart + b3) @ Wl  (3 coltiles x 32 experts, K=256; zsum folded)
  ff_kernel<3><<<dim3(3, 32), 256, 0, stream>>>(nullptr, Wl, b3, OutS, zpart,
                                                offsets, counts, tok_list);
  // combine: y = sum_k w_k (OutS + bl)
  combine_kernel<<<NTOK, 192, 0, stream>>>(OutS, bl, topk_idx, topk_w, tok2slot, y);
}